// Round 4
// baseline (190.627 us; speedup 1.0000x reference)
//
#include <hip/hip_runtime.h>
#include <math.h>

#define NN 512   // set size / rows of feat_x
#define IN 512   // INPUT_DIM
#define HD 256   // HIDDEN_DIM
#define RD 256   // REP_DIM
#define SH 128   // SCORE_HIDDEN

// Branchless erf-GELU, Abramowitz-Stegun 7.1.26 (|erf err| <= 1.5e-7).
__device__ __forceinline__ float gelu_fast(float x){
    const float z  = x * 0.70710678118654752f;
    const float az = fabsf(z);
    const float t  = __builtin_amdgcn_rcpf(fmaf(0.3275911f, az, 1.0f));
    float p = fmaf(1.061405429f, t, -1.453152027f);
    p = fmaf(p, t, 1.421413741f);
    p = fmaf(p, t, -0.284496736f);
    p = fmaf(p, t, 0.254829592f);
    p = p * t;
    const float e = __builtin_amdgcn_exp2f(z * z * -1.4426950408889634f);
    const float E = p * e;                        // erfc(|z|)
    const float one_plus_erf = (x >= 0.0f) ? (2.0f - E) : E;
    return 0.5f * x * one_plus_erf;
}

// K_G1: h = GELU(feat @ g_w1 + b1), feat = [x;pos;neg] stacked (1536 x 512).
__global__ __launch_bounds__(256) void k_g1(
    const float* __restrict__ fx, const float* __restrict__ fp, const float* __restrict__ fn,
    const float* __restrict__ w1, const float* __restrict__ b1,
    float* __restrict__ h)
{
    __shared__ float xs[4][IN];      // 8 KB
    __shared__ float ps[32][128];    // 16 KB
    const int t = threadIdx.x;
    const int mat = blockIdx.x >> 8;
    const int rem = blockIdx.x & 255;
    const int row0 = (rem >> 1) << 2;
    const int colbase = (rem & 1) << 7;
    const float* src = (mat==0) ? fx : (mat==1) ? fp : fn;

    #pragma unroll
    for (int rep=0; rep<2; rep++){
        int f = rep*256 + t;
        int j = f >> 7, c4 = (f & 127) << 2;
        *(float4*)&xs[j][c4] = *(const float4*)&src[(row0+j)*IN + c4];
    }
    __syncthreads();

    const int cg = t & 31, s = t >> 5;
    const int c0 = cg << 2;
    float4 acc[4];
    #pragma unroll
    for (int j=0;j<4;j++) acc[j] = make_float4(0.f,0.f,0.f,0.f);

    const float* wp = w1 + (s*64)*HD + colbase + c0;
    #pragma unroll 8
    for (int ii=0; ii<64; ii++){
        float4 w = *(const float4*)wp; wp += HD;
        const int i = s*64 + ii;
        #pragma unroll
        for (int j=0;j<4;j++){
            const float xv = xs[j][i];
            acc[j].x = fmaf(xv, w.x, acc[j].x);
            acc[j].y = fmaf(xv, w.y, acc[j].y);
            acc[j].z = fmaf(xv, w.z, acc[j].z);
            acc[j].w = fmaf(xv, w.w, acc[j].w);
        }
    }
    #pragma unroll
    for (int j=0;j<4;j++) *(float4*)&ps[s*4+j][c0] = acc[j];
    __syncthreads();

    #pragma unroll
    for (int rep=0; rep<2; rep++){
        const int idx = rep*256 + t;
        const int j = idx >> 7, c = idx & 127;
        float v = 0.f;
        #pragma unroll
        for (int ss=0; ss<8; ss++) v += ps[ss*4+j][c];
        h[(mat*NN + row0 + j)*HD + colbase + c] = gelu_fast(v + b1[colbase + c]);
    }
}

// K_G2AB: rep = h @ g_w2 + b2 (full 256 cols, 4 rows/block), then in-block:
//   A_x / BT projections of the score net + transposed rep copies + row norms.
__global__ __launch_bounds__(256) void k_g2ab(
    const float* __restrict__ h,
    const float* __restrict__ w2, const float* __restrict__ b2,
    const float* __restrict__ s_w1,
    float* __restrict__ r_x, float* __restrict__ r_p, float* __restrict__ r_n,
    float* __restrict__ r_pT, float* __restrict__ r_nT,
    float* __restrict__ A_x, float* __restrict__ BT_p, float* __restrict__ BT_n,
    float* __restrict__ nx2, float* __restrict__ np2, float* __restrict__ nn2)
{
    __shared__ float xs[4][HD];       // 4 KB
    __shared__ float ps[16][RD];      // 16 KB
    __shared__ float rloc[4][RD+4];   // padded: transpose reads conflict-free
    __shared__ float ab[4][SH+4];
    const int t = threadIdx.x;
    const int mat = blockIdx.x >> 7;
    const int row0 = (blockIdx.x & 127) << 2;

    {
        int j = t >> 6, c4 = (t & 63) << 2;
        *(float4*)&xs[j][c4] = *(const float4*)&h[(mat*NN + row0 + j)*HD + c4];
    }
    __syncthreads();

    // GEMM2: 4 rows x 256 cols, 4 K-slices of 64
    {
        const int cg = t & 63, s = t >> 6;
        const int c0 = cg << 2;
        float4 acc[4];
        #pragma unroll
        for (int j=0;j<4;j++) acc[j] = make_float4(0.f,0.f,0.f,0.f);
        const float* wp = w2 + (s*64)*RD + c0;
        #pragma unroll 8
        for (int ii=0; ii<64; ii++){
            float4 w = *(const float4*)wp; wp += RD;
            const int i = s*64 + ii;
            #pragma unroll
            for (int j=0;j<4;j++){
                const float xv = xs[j][i];
                acc[j].x = fmaf(xv, w.x, acc[j].x);
                acc[j].y = fmaf(xv, w.y, acc[j].y);
                acc[j].z = fmaf(xv, w.z, acc[j].z);
                acc[j].w = fmaf(xv, w.w, acc[j].w);
            }
        }
        #pragma unroll
        for (int j=0;j<4;j++) *(float4*)&ps[s*4+j][c0] = acc[j];
    }
    __syncthreads();

    // reduce K-slices + bias -> rloc + coalesced global r
    float* rout = (mat==0) ? r_x : (mat==1) ? r_p : r_n;
    #pragma unroll
    for (int rep=0; rep<4; rep++){
        const int idx = rep*256 + t;
        const int j = idx >> 8, c = idx & 255;
        float v = b2[c];
        #pragma unroll
        for (int ss=0; ss<4; ss++) v += ps[ss*4+j][c];
        rloc[j][c] = v;
        rout[(row0+j)*RD + c] = v;
    }
    __syncthreads();

    // transposed rep copy (pos/neg): float4 across the 4 rows
    if (mat && t < 256){
        float* rT = (mat==1) ? r_pT : r_nT;
        float4 q = make_float4(rloc[0][t], rloc[1][t], rloc[2][t], rloc[3][t]);
        *(float4*)&rT[t*NN + row0] = q;
    }

    // squared row norms (wave w handles row w)
    {
        const int lane = t & 63, w = t >> 6;
        float v = 0.f;
        #pragma unroll
        for (int q=0;q<4;q++){ const float r = rloc[w][lane + 64*q]; v = fmaf(r, r, v); }
        #pragma unroll
        for (int off=32; off>=1; off>>=1) v += __shfl_xor(v, off);
        if (lane==0){
            float* nrm = (mat==0) ? nx2 : (mat==1) ? np2 : nn2;
            nrm[row0 + w] = v;
        }
    }

    // score-net projection: A (mat0, w = w1x - w1d) / B (mat1/2, w = w1y + w1d)
    {
        const int c = t & 127, jb = (t >> 7) << 1;
        const float sgn = (mat==0) ? -1.0f : 1.0f;
        const int base1 = (mat==0) ? 0 : 256;
        const float* p1 = s_w1 + base1*SH + c;
        const float* p3 = s_w1 + 512*SH + c;
        float v0 = 0.f, v1 = 0.f;
        #pragma unroll 4
        for (int i=0;i<RD;i++){
            const float w = fmaf(sgn, p3[i*SH], p1[i*SH]);
            v0 = fmaf(rloc[jb][i],   w, v0);
            v1 = fmaf(rloc[jb+1][i], w, v1);
        }
        if (mat==0){
            A_x[(row0+jb)*SH + c]   = v0;
            A_x[(row0+jb+1)*SH + c] = v1;
        } else {
            ab[jb][c] = v0;
            ab[jb+1][c] = v1;
        }
    }
    __syncthreads();
    if (mat && t < 128){
        float* BT = (mat==1) ? BT_p : BT_n;
        float4 q = make_float4(ab[0][t], ab[1][t], ab[2][t], ab[3][t]);
        *(float4*)&BT[t*NN + row0] = q;
    }
}

// K_SD: unnormalized softmax numerators E = exp(logit) + per-mtile row sums.
// Block = (set, 8-row n-tile, 128-col m-tile); thread = (4 rows, 1 m).
// Max-free: logits ~ N(0,~0.7) by construction, exp() is fp32-safe unshifted.
__global__ __launch_bounds__(256) void k_sd(
    const float* __restrict__ r_x, const float* __restrict__ r_pT, const float* __restrict__ r_nT,
    const float* __restrict__ A_x, const float* __restrict__ BT_p, const float* __restrict__ BT_n,
    const float* __restrict__ nx2, const float* __restrict__ np2, const float* __restrict__ nn2,
    const float* __restrict__ s_w1, const float* __restrict__ s_b1,
    const float* __restrict__ s_w2, const float* __restrict__ s_b2,
    float* __restrict__ E_p, float* __restrict__ E_n, float* __restrict__ Spart)
{
    __shared__ float xrT[RD][8];      // 8 KB, transposed x-reps
    __shared__ float cmb[SH][12];     // 6 KB: [A+b1 rows 0..7, wn, w2, pad, pad]
    __shared__ float ny2v[128];
    __shared__ float nxv[8];
    __shared__ float ssum[8][2];
    const int t = threadIdx.x;
    const int set = blockIdx.x >> 8;
    const int rem = blockIdx.x & 255;
    const int n0 = (rem >> 2) << 3;
    const int mbase = (rem & 3) << 7;
    const int tm = t & 127, tn = t >> 7;
    const int m = mbase + tm;

    const float* yT = set ? r_nT : r_pT;
    const float* BT = set ? BT_n : BT_p;
    const float* ny2 = set ? nn2 : np2;
    float* E = set ? E_n : E_p;

    #pragma unroll
    for (int j=0;j<8;j++) xrT[t][j] = r_x[(n0+j)*RD + t];
    if (t < SH){
        #pragma unroll
        for (int j=0;j<8;j++) cmb[t][j] = A_x[(n0+j)*SH + t] + s_b1[t];
        cmb[t][8] = s_w1[768*SH + t];
        cmb[t][9] = s_w2[t];
        ny2v[t] = ny2[mbase + t];
    }
    if (t < 8) nxv[t] = nx2[n0 + t];
    __syncthreads();

    // phase 1: dots -> distances (Gram identity)
    float d0=0.f, d1=0.f, d2=0.f, d3=0.f;
    {
        const float* yp = yT + m;
        #pragma unroll 4
        for (int r=0; r<RD; r++){
            const float y = *yp; yp += NN;
            const float4 xv = *(const float4*)&xrT[r][tn*4];
            d0 = fmaf(xv.x, y, d0);
            d1 = fmaf(xv.y, y, d1);
            d2 = fmaf(xv.z, y, d2);
            d3 = fmaf(xv.w, y, d3);
        }
    }
    const float nyv = ny2v[tm];
    const float4 nx4 = *(const float4*)&nxv[tn*4];
    float dn[4];
    dn[0] = sqrtf(fmaxf(fmaf(-2.f, d0, nx4.x + nyv), 0.f));
    dn[1] = sqrtf(fmaxf(fmaf(-2.f, d1, nx4.y + nyv), 0.f));
    dn[2] = sqrtf(fmaxf(fmaf(-2.f, d2, nx4.z + nyv), 0.f));
    dn[3] = sqrtf(fmaxf(fmaf(-2.f, d3, nx4.w + nyv), 0.f));

    // phase 2: logits (decomposed score net)
    float a[4] = {0.f,0.f,0.f,0.f};
    {
        const float* bp = BT + m;
        #pragma unroll 2
        for (int k=0; k<SH; k++){
            const float b = *bp; bp += NN;
            const float4 cA = *(const float4*)&cmb[k][tn*4];
            const float2 wz = *(const float2*)&cmb[k][8];
            a[0] = fmaf(wz.y, gelu_fast(fmaf(dn[0], wz.x, cA.x + b)), a[0]);
            a[1] = fmaf(wz.y, gelu_fast(fmaf(dn[1], wz.x, cA.y + b)), a[1]);
            a[2] = fmaf(wz.y, gelu_fast(fmaf(dn[2], wz.x, cA.z + b)), a[2]);
            a[3] = fmaf(wz.y, gelu_fast(fmaf(dn[3], wz.x, cA.w + b)), a[3]);
        }
    }
    const float b2v = s_b2[0];
    const int wv2 = (t >> 6) & 1;
    float ee[4];
    #pragma unroll
    for (int j=0;j<4;j++){
        ee[j] = __builtin_amdgcn_exp2f((a[j] + b2v) * 1.4426950408889634f);
        E[(n0 + tn*4 + j)*NN + m] = ee[j];
    }
    #pragma unroll
    for (int j=0;j<4;j++){
        float v = ee[j];
        #pragma unroll
        for (int off=32; off>=1; off>>=1) v += __shfl_xor(v, off);
        if ((t & 63) == 0) ssum[tn*4+j][wv2] = v;
    }
    __syncthreads();
    if (t < 8){
        const int mt = rem & 3;
        Spart[(set*4 + mt)*NN + n0 + t] = ssum[t][0] + ssum[t][1];
    }
}

// K_FIN: normalize weights from E/Spart, then out[n] = (W_p@r_p - W_n@r_n) @ out_w.
__global__ __launch_bounds__(512) void k_fin(
    const float* __restrict__ E_p, const float* __restrict__ E_n,
    const float* __restrict__ Spart,
    const float* __restrict__ r_p, const float* __restrict__ r_n,
    const float* __restrict__ out_w, float* __restrict__ out)
{
    __shared__ float wp[2][NN];
    __shared__ float wq[2][NN];
    __shared__ float psA[16][RD];
    __shared__ float dv[2][RD];
    __shared__ float ps2[8][NN];
    const int t = threadIdx.x;
    const int n0 = blockIdx.x << 1;

    #pragma unroll
    for (int j=0;j<2;j++){
        const int n = n0 + j;
        float Sp = 0.f, Sn = 0.f;
        #pragma unroll
        for (int q=0;q<4;q++){
            Sp += Spart[q*NN + n];
            Sn += Spart[(4+q)*NN + n];
        }
        const float ip = 1.0f / Sp, in_ = 1.0f / Sn;
        wp[j][t] = E_p[n*NN + t] * ip;
        wq[j][t] = E_n[n*NN + t] * in_;
    }
    __syncthreads();

    {   // phase A: dv[j][c] = sum_m wp[j][m]*r_p[m][c] - wq[j][m]*r_n[m][c]
        const int cg = t & 63, s = t >> 6;
        const int c0 = cg << 2;
        float4 a0 = make_float4(0.f,0.f,0.f,0.f), a1 = a0;
        const float* pp = r_p + (s*64)*RD + c0;
        const float* pn = r_n + (s*64)*RD + c0;
        #pragma unroll 4
        for (int mm=0; mm<64; mm++){
            float4 yp4 = *(const float4*)pp; pp += RD;
            float4 yn4 = *(const float4*)pn; pn += RD;
            const int mI = s*64 + mm;
            const float w0 = wp[0][mI], w1v = wp[1][mI];
            const float q0 = wq[0][mI], q1v = wq[1][mI];
            a0.x = fmaf(w0, yp4.x, a0.x); a0.x = fmaf(-q0, yn4.x, a0.x);
            a0.y = fmaf(w0, yp4.y, a0.y); a0.y = fmaf(-q0, yn4.y, a0.y);
            a0.z = fmaf(w0, yp4.z, a0.z); a0.z = fmaf(-q0, yn4.z, a0.z);
            a0.w = fmaf(w0, yp4.w, a0.w); a0.w = fmaf(-q0, yn4.w, a0.w);
            a1.x = fmaf(w1v, yp4.x, a1.x); a1.x = fmaf(-q1v, yn4.x, a1.x);
            a1.y = fmaf(w1v, yp4.y, a1.y); a1.y = fmaf(-q1v, yn4.y, a1.y);
            a1.z = fmaf(w1v, yp4.z, a1.z); a1.z = fmaf(-q1v, yn4.z, a1.z);
            a1.w = fmaf(w1v, yp4.w, a1.w); a1.w = fmaf(-q1v, yn4.w, a1.w);
        }
        *(float4*)&psA[s*2+0][c0] = a0;
        *(float4*)&psA[s*2+1][c0] = a1;
    }
    __syncthreads();

    {
        const int j = t >> 8, c = t & 255;
        float v = 0.f;
        #pragma unroll
        for (int ss=0; ss<8; ss++) v += psA[ss*2+j][c];
        dv[j][c] = v;
    }
    __syncthreads();

    {   // phase B: out[j][c] = sum_r dv[j][r]*out_w[r][c]
        const int og = t & 127, s = t >> 7;
        const int c0 = og << 2;
        float4 a0 = make_float4(0.f,0.f,0.f,0.f), a1 = a0;
        const float* wo = out_w + (s*64)*IN + c0;
        #pragma unroll 4
        for (int rr=0; rr<64; rr++){
            float4 w = *(const float4*)wo; wo += IN;
            const int r = s*64 + rr;
            const float d0 = dv[0][r], d1 = dv[1][r];
            a0.x = fmaf(d0, w.x, a0.x); a0.y = fmaf(d0, w.y, a0.y);
            a0.z = fmaf(d0, w.z, a0.z); a0.w = fmaf(d0, w.w, a0.w);
            a1.x = fmaf(d1, w.x, a1.x); a1.y = fmaf(d1, w.y, a1.y);
            a1.z = fmaf(d1, w.z, a1.z); a1.w = fmaf(d1, w.w, a1.w);
        }
        *(float4*)&ps2[s*2+0][c0] = a0;
        *(float4*)&ps2[s*2+1][c0] = a1;
    }
    __syncthreads();

    {
        const int c = t;
        #pragma unroll
        for (int j=0;j<2;j++){
            float v = 0.f;
            #pragma unroll
            for (int ss=0; ss<4; ss++) v += ps2[ss*2+j][c];
            out[(n0+j)*IN + c] = v;
        }
    }
}

extern "C" void kernel_launch(void* const* d_in, const int* in_sizes, int n_in,
                              void* d_out, int out_size, void* d_ws, size_t ws_size,
                              hipStream_t stream)
{
    const float* fx  = (const float*)d_in[0];
    const float* fp  = (const float*)d_in[1];
    const float* fn  = (const float*)d_in[2];
    const float* gw1 = (const float*)d_in[3];
    const float* gb1 = (const float*)d_in[4];
    const float* gw2 = (const float*)d_in[5];
    const float* gb2 = (const float*)d_in[6];
    const float* ow  = (const float*)d_in[7];
    const float* sw1 = (const float*)d_in[8];
    const float* sb1 = (const float*)d_in[9];
    const float* sw2 = (const float*)d_in[10];
    const float* sb2 = (const float*)d_in[11];
    float* out = (float*)d_out;

    float* ws   = (float*)d_ws;
    float* r_x  = ws;               // 512*256
    float* r_p  = r_x  + 131072;
    float* r_n  = r_p  + 131072;
    float* r_pT = r_n  + 131072;    // 256*512
    float* r_nT = r_pT + 131072;
    float* A_x  = r_nT + 131072;    // 512*128
    float* BT_p = A_x  + 65536;     // 128*512
    float* BT_n = BT_p + 65536;
    float* nx2  = BT_n + 65536;     // 512
    float* np2  = nx2  + 512;
    float* nn2  = np2  + 512;
    float* E_p  = nn2  + 512;       // 512*512
    float* E_n  = E_p  + 262144;
    float* Spar = E_n  + 262144;    // 2*4*512
    float* hbuf = Spar + 4096;      // 1536*256

    hipLaunchKernelGGL(k_g1, dim3(768), dim3(256), 0, stream,
                       fx, fp, fn, gw1, gb1, hbuf);
    hipLaunchKernelGGL(k_g2ab, dim3(384), dim3(256), 0, stream,
                       hbuf, gw2, gb2, sw1, r_x, r_p, r_n, r_pT, r_nT,
                       A_x, BT_p, BT_n, nx2, np2, nn2);
    hipLaunchKernelGGL(k_sd, dim3(512), dim3(256), 0, stream,
                       r_x, r_pT, r_nT, A_x, BT_p, BT_n, nx2, np2, nn2,
                       sw1, sb1, sw2, sb2, E_p, E_n, Spar);
    hipLaunchKernelGGL(k_fin, dim3(256), dim3(512), 0, stream,
                       E_p, E_n, Spar, r_p, r_n, ow, out);
}

// Round 5
// 183.732 us; speedup vs baseline: 1.0375x; 1.0375x over previous
//
#include <hip/hip_runtime.h>
#include <math.h>

#define NN 512   // set size / rows of feat_x
#define IN 512   // INPUT_DIM
#define HD 256   // HIDDEN_DIM
#define RD 256   // REP_DIM
#define SH 128   // SCORE_HIDDEN

// Branchless erf-GELU, Abramowitz-Stegun 7.1.26 (|erf err| <= 1.5e-7).
__device__ __forceinline__ float gelu_fast(float x){
    const float z  = x * 0.70710678118654752f;
    const float az = fabsf(z);
    const float t  = __builtin_amdgcn_rcpf(fmaf(0.3275911f, az, 1.0f));
    float p = fmaf(1.061405429f, t, -1.453152027f);
    p = fmaf(p, t, 1.421413741f);
    p = fmaf(p, t, -0.284496736f);
    p = fmaf(p, t, 0.254829592f);
    p = p * t;
    const float e = __builtin_amdgcn_exp2f(z * z * -1.4426950408889634f);
    const float E = p * e;                        // erfc(|z|)
    const float one_plus_erf = (x >= 0.0f) ? (2.0f - E) : E;
    return 0.5f * x * one_plus_erf;
}

// K_G1: h = GELU(feat @ g_w1 + b1), feat = [x;pos;neg] stacked (1536 x 512).
__global__ __launch_bounds__(256) void k_g1(
    const float* __restrict__ fx, const float* __restrict__ fp, const float* __restrict__ fn,
    const float* __restrict__ w1, const float* __restrict__ b1,
    float* __restrict__ h)
{
    __shared__ float xs[4][IN];      // 8 KB
    __shared__ float ps[32][128];    // 16 KB
    const int t = threadIdx.x;
    const int mat = blockIdx.x >> 8;
    const int rem = blockIdx.x & 255;
    const int row0 = (rem >> 1) << 2;
    const int colbase = (rem & 1) << 7;
    const float* src = (mat==0) ? fx : (mat==1) ? fp : fn;

    #pragma unroll
    for (int rep=0; rep<2; rep++){
        int f = rep*256 + t;
        int j = f >> 7, c4 = (f & 127) << 2;
        *(float4*)&xs[j][c4] = *(const float4*)&src[(row0+j)*IN + c4];
    }
    __syncthreads();

    const int cg = t & 31, s = t >> 5;
    const int c0 = cg << 2;
    float4 acc[4];
    #pragma unroll
    for (int j=0;j<4;j++) acc[j] = make_float4(0.f,0.f,0.f,0.f);

    const float* wp = w1 + (s*64)*HD + colbase + c0;
    #pragma unroll 8
    for (int ii=0; ii<64; ii++){
        float4 w = *(const float4*)wp; wp += HD;
        const int i = s*64 + ii;
        #pragma unroll
        for (int j=0;j<4;j++){
            const float xv = xs[j][i];
            acc[j].x = fmaf(xv, w.x, acc[j].x);
            acc[j].y = fmaf(xv, w.y, acc[j].y);
            acc[j].z = fmaf(xv, w.z, acc[j].z);
            acc[j].w = fmaf(xv, w.w, acc[j].w);
        }
    }
    #pragma unroll
    for (int j=0;j<4;j++) *(float4*)&ps[s*4+j][c0] = acc[j];
    __syncthreads();

    #pragma unroll
    for (int rep=0; rep<2; rep++){
        const int idx = rep*256 + t;
        const int j = idx >> 7, c = idx & 127;
        float v = 0.f;
        #pragma unroll
        for (int ss=0; ss<8; ss++) v += ps[ss*4+j][c];
        h[(mat*NN + row0 + j)*HD + colbase + c] = gelu_fast(v + b1[colbase + c]);
    }
}

// K_G2: rep = h @ g_w2 + b2 (1536 x 256) + transposed copies for pos/neg.
// 4 rows x 128-col half per block -> 768 blocks (3/CU).
__global__ __launch_bounds__(256) void k_g2(
    const float* __restrict__ h,
    const float* __restrict__ w2, const float* __restrict__ b2,
    float* __restrict__ r_x, float* __restrict__ r_p, float* __restrict__ r_n,
    float* __restrict__ r_pT, float* __restrict__ r_nT)
{
    __shared__ float xs[4][HD];      // 4 KB
    __shared__ float ps[32][128];    // 16 KB
    __shared__ float rloc[4][132];
    const int t = threadIdx.x;
    const int mat = blockIdx.x >> 8;
    const int rem = blockIdx.x & 255;
    const int row0 = (rem >> 1) << 2;
    const int colbase = (rem & 1) << 7;

    {
        int j = t >> 6, c4 = (t & 63) << 2;
        *(float4*)&xs[j][c4] = *(const float4*)&h[(mat*NN + row0 + j)*HD + c4];
    }
    __syncthreads();

    const int cg = t & 31, s = t >> 5;
    const int c0 = cg << 2;
    float4 acc[4];
    #pragma unroll
    for (int j=0;j<4;j++) acc[j] = make_float4(0.f,0.f,0.f,0.f);

    const float* wp = w2 + (s*32)*RD + colbase + c0;
    #pragma unroll 8
    for (int ii=0; ii<32; ii++){
        float4 w = *(const float4*)wp; wp += RD;
        const int i = s*32 + ii;
        #pragma unroll
        for (int j=0;j<4;j++){
            const float xv = xs[j][i];
            acc[j].x = fmaf(xv, w.x, acc[j].x);
            acc[j].y = fmaf(xv, w.y, acc[j].y);
            acc[j].z = fmaf(xv, w.z, acc[j].z);
            acc[j].w = fmaf(xv, w.w, acc[j].w);
        }
    }
    #pragma unroll
    for (int j=0;j<4;j++) *(float4*)&ps[s*4+j][c0] = acc[j];
    __syncthreads();

    float* rout = (mat==0) ? r_x : (mat==1) ? r_p : r_n;
    #pragma unroll
    for (int rep=0; rep<2; rep++){
        const int idx = rep*256 + t;
        const int j = idx >> 7, c = idx & 127;
        float v = b2[colbase + c];
        #pragma unroll
        for (int ss=0; ss<8; ss++) v += ps[ss*4+j][c];
        rloc[j][c] = v;
        rout[(row0+j)*RD + colbase + c] = v;
    }
    __syncthreads();
    if (mat && t < 128){
        float* rT = (mat==1) ? r_pT : r_nT;
        float4 q = make_float4(rloc[0][t], rloc[1][t], rloc[2][t], rloc[3][t]);
        *(float4*)&rT[(colbase + t)*NN + row0] = q;
    }
}

// K_AB: A_x = r_x @ (w1x - w1d);  BT_y = [r_y @ (w1y + w1d)]^T.
// 2 rows/block -> 768 blocks (3/CU), 32 colgroups x 8 K-slices.
__global__ __launch_bounds__(256) void k_ab(
    const float* __restrict__ r_x, const float* __restrict__ r_p, const float* __restrict__ r_n,
    const float* __restrict__ s_w1,
    float* __restrict__ A_x, float* __restrict__ BT_p, float* __restrict__ BT_n)
{
    __shared__ float xs[2][RD];       // 2 KB
    __shared__ float ps[16][SH];      // 8 KB
    __shared__ float ab2[2][SH];
    const int t = threadIdx.x;
    const int mat = blockIdx.x >> 8;
    const int row0 = (blockIdx.x & 255) << 1;
    const float* src = (mat==0) ? r_x : (mat==1) ? r_p : r_n;
    if (t < 128){
        int j = t >> 6, c4 = (t & 63) << 2;
        *(float4*)&xs[j][c4] = *(const float4*)&src[(row0+j)*RD + c4];
    }
    __syncthreads();

    const int cg = t & 31, s = t >> 5;
    const int c0 = cg << 2;
    float4 a0 = make_float4(0.f,0.f,0.f,0.f), a1 = a0;

    const float sgn = (mat==0) ? -1.0f : 1.0f;
    const int base1 = (mat==0) ? 0 : 256;
    const float* p1 = s_w1 + (base1 + s*32)*SH + c0;
    const float* p3 = s_w1 + (512   + s*32)*SH + c0;
    #pragma unroll 8
    for (int ii=0; ii<32; ii++){
        float4 wa = *(const float4*)p1; p1 += SH;
        float4 wd = *(const float4*)p3; p3 += SH;
        float4 w;
        w.x = fmaf(sgn, wd.x, wa.x);
        w.y = fmaf(sgn, wd.y, wa.y);
        w.z = fmaf(sgn, wd.z, wa.z);
        w.w = fmaf(sgn, wd.w, wa.w);
        const int i = s*32 + ii;
        const float x0 = xs[0][i], x1 = xs[1][i];
        a0.x = fmaf(x0, w.x, a0.x); a0.y = fmaf(x0, w.y, a0.y);
        a0.z = fmaf(x0, w.z, a0.z); a0.w = fmaf(x0, w.w, a0.w);
        a1.x = fmaf(x1, w.x, a1.x); a1.y = fmaf(x1, w.y, a1.y);
        a1.z = fmaf(x1, w.z, a1.z); a1.w = fmaf(x1, w.w, a1.w);
    }
    *(float4*)&ps[s*2+0][c0] = a0;
    *(float4*)&ps[s*2+1][c0] = a1;
    __syncthreads();

    {
        const int j = t >> 7, c = t & 127;
        float v = 0.f;
        #pragma unroll
        for (int ss=0; ss<8; ss++) v += ps[ss*2+j][c];
        if (mat==0) A_x[(row0+j)*SH + c] = v;
        else        ab2[j][c] = v;
    }
    __syncthreads();
    if (mat && t < 128){
        float* BT = (mat==1) ? BT_p : BT_n;
        *(float2*)&BT[t*NN + row0] = make_float2(ab2[0][t], ab2[1][t]);
    }
}

// K_SD: unnormalized softmax numerators E = exp(logit) + per-mtile row sums.
// Block = (set, 4-row n-tile, 128-col m-tile) -> 1024 blocks (4/CU, 16 waves).
// Norms computed in-kernel: y^2 rides the phase-1 loop; x^2 from LDS.
__global__ __launch_bounds__(256) void k_sd(
    const float* __restrict__ r_x, const float* __restrict__ r_pT, const float* __restrict__ r_nT,
    const float* __restrict__ A_x, const float* __restrict__ BT_p, const float* __restrict__ BT_n,
    const float* __restrict__ s_w1, const float* __restrict__ s_b1,
    const float* __restrict__ s_w2,
    float* __restrict__ E_p, float* __restrict__ E_n, float* __restrict__ Spart)
{
    __shared__ float2 xs2[2][RD];     // 4 KB: {rows 0,1} and {rows 2,3}
    __shared__ float4 cA4[SH];        // 2 KB: A+b1 for rows 0..3
    __shared__ float2 wz2[SH];        // 1 KB: {w_norm, w2}
    __shared__ float nyv[128];
    __shared__ float nxv[4];
    __shared__ float ssum[4][2];
    const int t = threadIdx.x;
    const int set = blockIdx.x >> 9;
    const int rem = blockIdx.x & 511;
    const int n0 = (rem >> 2) << 2;
    const int mt = rem & 3;
    const int mbase = mt << 7;
    const int tm = t & 127, tn = t >> 7;
    const int m = mbase + tm;
    const float* yT = set ? r_nT : r_pT;
    const float* BT = set ? BT_n : BT_p;
    float* E = set ? E_n : E_p;

    xs2[0][t] = make_float2(r_x[(n0+0)*RD + t], r_x[(n0+1)*RD + t]);
    xs2[1][t] = make_float2(r_x[(n0+2)*RD + t], r_x[(n0+3)*RD + t]);
    if (t < SH){
        const float b1v = s_b1[t];
        cA4[t] = make_float4(A_x[(n0+0)*SH+t] + b1v, A_x[(n0+1)*SH+t] + b1v,
                             A_x[(n0+2)*SH+t] + b1v, A_x[(n0+3)*SH+t] + b1v);
        wz2[t] = make_float2(s_w1[768*SH + t], s_w2[t]);
    }
    __syncthreads();

    // x-row norms: wave jj handles row jj
    {
        const int jj = t >> 6, lane = t & 63;
        const int p = jj >> 1, u = jj & 1;
        float v = 0.f;
        #pragma unroll
        for (int q=0;q<4;q++){
            const float2 e = xs2[p][lane + 64*q];
            const float ev = u ? e.y : e.x;
            v = fmaf(ev, ev, v);
        }
        #pragma unroll
        for (int off=32; off>=1; off>>=1) v += __shfl_xor(v, off);
        if (lane==0) nxv[jj] = v;
    }

    // phase 1: dots + y-norm (Gram identity)
    float d0=0.f, d1=0.f, ny=0.f;
    {
        const float* yp = yT + m;
        #pragma unroll 8
        for (int r=0; r<RD; r++){
            const float y = *yp; yp += NN;
            const float2 xv = xs2[tn][r];
            d0 = fmaf(xv.x, y, d0);
            d1 = fmaf(xv.y, y, d1);
            ny = fmaf(y, y, ny);
        }
    }
    if (tn==0) nyv[tm] = ny;
    __syncthreads();
    const float nyc = nyv[tm];
    const int j0 = tn << 1;
    const float dn0 = sqrtf(fmaxf(fmaf(-2.f, d0, nxv[j0]   + nyc), 0.f));
    const float dn1 = sqrtf(fmaxf(fmaf(-2.f, d1, nxv[j0+1] + nyc), 0.f));

    // phase 2: logits (decomposed score net), 2 rows/thread
    float a0=0.f, a1=0.f;
    {
        const float* bp = BT + m;
        const float* cbase = (const float*)cA4 + (tn << 1);
        #pragma unroll 2
        for (int k=0; k<SH; k++){
            const float b = *bp; bp += NN;
            const float2 c2 = *(const float2*)(cbase + (k << 2));
            const float2 wz = wz2[k];
            a0 = fmaf(wz.y, gelu_fast(fmaf(dn0, wz.x, c2.x + b)), a0);
            a1 = fmaf(wz.y, gelu_fast(fmaf(dn1, wz.x, c2.y + b)), a1);
        }
    }
    // s_b2 omitted: softmax is shift-invariant
    const float e0 = __builtin_amdgcn_exp2f(a0 * 1.4426950408889634f);
    const float e1 = __builtin_amdgcn_exp2f(a1 * 1.4426950408889634f);
    E[(n0+j0  )*NN + m] = e0;
    E[(n0+j0+1)*NN + m] = e1;

    const int wv = (t >> 6) & 1;
    float v0 = e0, v1 = e1;
    #pragma unroll
    for (int off=32; off>=1; off>>=1){ v0 += __shfl_xor(v0, off); v1 += __shfl_xor(v1, off); }
    if ((t & 63) == 0){ ssum[j0][wv] = v0; ssum[j0+1][wv] = v1; }
    __syncthreads();
    if (t < 4) Spart[(set*4 + mt)*NN + n0 + t] = ssum[t][0] + ssum[t][1];
}

// K_DV: partial einsum over a 64-m slice, both sets combined (pos - neg).
// Block = (8-row n-tile, 64-m slice) -> 512 blocks. psum[ms][n][c].
__global__ __launch_bounds__(256) void k_dv(
    const float* __restrict__ E_p, const float* __restrict__ E_n,
    const float* __restrict__ Spart,
    const float* __restrict__ r_p, const float* __restrict__ r_n,
    float* __restrict__ psum)
{
    __shared__ float rinv[16];        // [set*8+j]
    __shared__ float wbuf[2][64][8];  // [set][m][j]
    const int t = threadIdx.x;
    const int nt = blockIdx.x >> 3;
    const int ms = blockIdx.x & 7;
    const int n0 = nt << 3, mbase = ms << 6;

    if (t < 16){
        const int se = t >> 3, n = n0 + (t & 7);
        float S = 0.f;
        #pragma unroll
        for (int q=0;q<4;q++) S += Spart[(se*4+q)*NN + n];
        rinv[t] = 1.0f / S;
    }
    __syncthreads();
    #pragma unroll
    for (int rep=0; rep<4; rep++){
        const int idx = rep*256 + t;
        const int se = idx >> 9, j = (idx >> 6) & 7, mm = idx & 63;
        const float* E = se ? E_n : E_p;
        wbuf[se][mm][j] = E[(n0+j)*NN + mbase + mm] * rinv[se*8 + j];
    }
    __syncthreads();

    float acc[8] = {0,0,0,0,0,0,0,0};
    {
        const float* rp = r_p + mbase*RD + t;
        #pragma unroll 4
        for (int mm=0; mm<64; mm++){
            const float rv = *rp; rp += RD;
            const float4 wa = *(const float4*)&wbuf[0][mm][0];
            const float4 wb = *(const float4*)&wbuf[0][mm][4];
            acc[0]=fmaf(wa.x,rv,acc[0]); acc[1]=fmaf(wa.y,rv,acc[1]);
            acc[2]=fmaf(wa.z,rv,acc[2]); acc[3]=fmaf(wa.w,rv,acc[3]);
            acc[4]=fmaf(wb.x,rv,acc[4]); acc[5]=fmaf(wb.y,rv,acc[5]);
            acc[6]=fmaf(wb.z,rv,acc[6]); acc[7]=fmaf(wb.w,rv,acc[7]);
        }
    }
    {
        const float* rp = r_n + mbase*RD + t;
        #pragma unroll 4
        for (int mm=0; mm<64; mm++){
            const float rv = -(*rp); rp += RD;
            const float4 wa = *(const float4*)&wbuf[1][mm][0];
            const float4 wb = *(const float4*)&wbuf[1][mm][4];
            acc[0]=fmaf(wa.x,rv,acc[0]); acc[1]=fmaf(wa.y,rv,acc[1]);
            acc[2]=fmaf(wa.z,rv,acc[2]); acc[3]=fmaf(wa.w,rv,acc[3]);
            acc[4]=fmaf(wb.x,rv,acc[4]); acc[5]=fmaf(wb.y,rv,acc[5]);
            acc[6]=fmaf(wb.z,rv,acc[6]); acc[7]=fmaf(wb.w,rv,acc[7]);
        }
    }
    float* P = psum + ms*(NN*RD);
    #pragma unroll
    for (int j=0;j<8;j++) P[(n0+j)*RD + t] = acc[j];
}

// K_OUT: dv = sum_ms psum; out = dv @ out_w. Block = (4-row n-tile, 128-col tile).
__global__ __launch_bounds__(256) void k_out(
    const float* __restrict__ psum, const float* __restrict__ out_w,
    float* __restrict__ out)
{
    __shared__ float4 dv4[RD];        // 4 KB: {dv rows 0..3}[r]
    __shared__ float ps[2][4][128];   // 4 KB
    const int t = threadIdx.x;
    const int nt = blockIdx.x >> 2;
    const int cb = (blockIdx.x & 3) << 7;
    const int n0 = nt << 2;

    {
        float v[4];
        #pragma unroll
        for (int j=0;j<4;j++){
            float s = 0.f;
            #pragma unroll
            for (int ms=0; ms<8; ms++) s += psum[ms*(NN*RD) + (n0+j)*RD + t];
            v[j] = s;
        }
        dv4[t] = make_float4(v[0], v[1], v[2], v[3]);
    }
    __syncthreads();

    const int cc = t & 127, s = t >> 7;
    float a0=0.f, a1=0.f, a2=0.f, a3=0.f;
    const float* wo = out_w + (s*128)*IN + cb + cc;
    #pragma unroll 4
    for (int rr=0; rr<128; rr++){
        const float w = *wo; wo += IN;
        const float4 d = dv4[s*128 + rr];
        a0 = fmaf(d.x, w, a0);
        a1 = fmaf(d.y, w, a1);
        a2 = fmaf(d.z, w, a2);
        a3 = fmaf(d.w, w, a3);
    }
    ps[s][0][cc] = a0; ps[s][1][cc] = a1; ps[s][2][cc] = a2; ps[s][3][cc] = a3;
    __syncthreads();
    if (t < 128){
        #pragma unroll
        for (int j=0;j<4;j++)
            out[(n0+j)*IN + cb + t] = ps[0][j][t] + ps[1][j][t];
    }
}

extern "C" void kernel_launch(void* const* d_in, const int* in_sizes, int n_in,
                              void* d_out, int out_size, void* d_ws, size_t ws_size,
                              hipStream_t stream)
{
    const float* fx  = (const float*)d_in[0];
    const float* fp  = (const float*)d_in[1];
    const float* fn  = (const float*)d_in[2];
    const float* gw1 = (const float*)d_in[3];
    const float* gb1 = (const float*)d_in[4];
    const float* gw2 = (const float*)d_in[5];
    const float* gb2 = (const float*)d_in[6];
    const float* ow  = (const float*)d_in[7];
    const float* sw1 = (const float*)d_in[8];
    const float* sb1 = (const float*)d_in[9];
    const float* sw2 = (const float*)d_in[10];
    float* out = (float*)d_out;

    float* ws   = (float*)d_ws;
    float* r_x  = ws;               // 512*256
    float* r_p  = r_x  + 131072;
    float* r_n  = r_p  + 131072;
    float* r_pT = r_n  + 131072;    // 256*512
    float* r_nT = r_pT + 131072;
    float* A_x  = r_nT + 131072;    // 512*128
    float* BT_p = A_x  + 65536;     // 128*512
    float* BT_n = BT_p + 65536;
    float* E_p  = BT_n + 65536;     // 512*512
    float* E_n  = E_p  + 262144;
    float* Spar = E_n  + 262144;    // 2*4*512
    float* hbuf = Spar + 4096;      // 1536*256
    float* psum = hbuf + 393216;    // 8*512*256 = 1M floats

    hipLaunchKernelGGL(k_g1, dim3(768), dim3(256), 0, stream,
                       fx, fp, fn, gw1, gb1, hbuf);
    hipLaunchKernelGGL(k_g2, dim3(768), dim3(256), 0, stream,
                       hbuf, gw2, gb2, r_x, r_p, r_n, r_pT, r_nT);
    hipLaunchKernelGGL(k_ab, dim3(768), dim3(256), 0, stream,
                       r_x, r_p, r_n, sw1, A_x, BT_p, BT_n);
    hipLaunchKernelGGL(k_sd, dim3(1024), dim3(256), 0, stream,
                       r_x, r_pT, r_nT, A_x, BT_p, BT_n,
                       sw1, sb1, sw2, E_p, E_n, Spar);
    hipLaunchKernelGGL(k_dv, dim3(512), dim3(256), 0, stream,
                       E_p, E_n, Spar, r_p, r_n, psum);
    hipLaunchKernelGGL(k_out, dim3(512), dim3(256), 0, stream,
                       psum, ow, out);
}

// Round 6
// 175.577 us; speedup vs baseline: 1.0857x; 1.0464x over previous
//
#include <hip/hip_runtime.h>
#include <math.h>

#define NN 512   // set size / rows of feat_x
#define IN 512   // INPUT_DIM
#define HD 256   // HIDDEN_DIM
#define RD 256   // REP_DIM
#define SH 128   // SCORE_HIDDEN

// Branchless erf-GELU, Abramowitz-Stegun 7.1.26 (|erf err| <= 1.5e-7).
__device__ __forceinline__ float gelu_fast(float x){
    const float z  = x * 0.70710678118654752f;
    const float az = fabsf(z);
    const float t  = __builtin_amdgcn_rcpf(fmaf(0.3275911f, az, 1.0f));
    float p = fmaf(1.061405429f, t, -1.453152027f);
    p = fmaf(p, t, 1.421413741f);
    p = fmaf(p, t, -0.284496736f);
    p = fmaf(p, t, 0.254829592f);
    p = p * t;
    const float e = __builtin_amdgcn_exp2f(z * z * -1.4426950408889634f);
    const float E = p * e;                        // erfc(|z|)
    const float one_plus_erf = (x >= 0.0f) ? (2.0f - E) : E;
    return 0.5f * x * one_plus_erf;
}

// K_REP: fused g-MLP + score-net projections. 384 blocks (3 mats x 128 rowgroups
// of 4 rows) x 512 threads. h and rep stay in LDS; writes r, rT, A_x, BT.
__global__ __launch_bounds__(512) void k_rep(
    const float* __restrict__ fx, const float* __restrict__ fp, const float* __restrict__ fn,
    const float* __restrict__ w1, const float* __restrict__ b1,
    const float* __restrict__ w2, const float* __restrict__ b2,
    const float* __restrict__ s_w1,
    float* __restrict__ r_x, float* __restrict__ r_p, float* __restrict__ r_n,
    float* __restrict__ r_pT, float* __restrict__ r_nT,
    float* __restrict__ A_x, float* __restrict__ BT_p, float* __restrict__ BT_n)
{
    __shared__ float xs[4][IN];        // 8 KB
    __shared__ float ps[8][4][HD];     // 32 KB partials (reused by all GEMM phases)
    __shared__ float hs[4][HD];        // 4 KB
    __shared__ float rloc[4][RD];      // 4 KB
    __shared__ float ab4[4][SH];       // 2 KB
    const int t = threadIdx.x;
    const int mat = blockIdx.x >> 7;
    const int row0 = (blockIdx.x & 127) << 2;
    const float* src = (mat==0) ? fx : (mat==1) ? fp : fn;

    {   // stage 4 feat rows: 512 float4s
        const int j = t >> 7, c4 = (t & 127) << 2;
        *(float4*)&xs[j][c4] = *(const float4*)&src[(row0+j)*IN + c4];
    }
    __syncthreads();

    const int cg = t & 63, s = t >> 6;   // 64 colgroups x 8 K-slices
    const int c0 = cg << 2;

    {   // GEMM1: K=512, slice [s*64, s*64+64)
        float4 acc[4];
        #pragma unroll
        for (int j=0;j<4;j++) acc[j] = make_float4(0.f,0.f,0.f,0.f);
        const float* wp = w1 + (s*64)*HD + c0;
        #pragma unroll 8
        for (int ii=0; ii<64; ii++){
            float4 w = *(const float4*)wp; wp += HD;
            const int i = s*64 + ii;
            #pragma unroll
            for (int j=0;j<4;j++){
                const float xv = xs[j][i];
                acc[j].x = fmaf(xv, w.x, acc[j].x);
                acc[j].y = fmaf(xv, w.y, acc[j].y);
                acc[j].z = fmaf(xv, w.z, acc[j].z);
                acc[j].w = fmaf(xv, w.w, acc[j].w);
            }
        }
        #pragma unroll
        for (int j=0;j<4;j++) *(float4*)&ps[s][j][c0] = acc[j];
    }
    __syncthreads();

    #pragma unroll
    for (int rep=0; rep<2; rep++){   // reduce + bias + GELU -> hs
        const int idx = rep*512 + t;
        const int j = idx >> 8, c = idx & 255;
        float v = b1[c];
        #pragma unroll
        for (int ss=0; ss<8; ss++) v += ps[ss][j][c];
        hs[j][c] = gelu_fast(v);
    }
    __syncthreads();

    {   // GEMM2: K=256, slice [s*32, s*32+32)
        float4 acc[4];
        #pragma unroll
        for (int j=0;j<4;j++) acc[j] = make_float4(0.f,0.f,0.f,0.f);
        const float* wp = w2 + (s*32)*RD + c0;
        #pragma unroll 8
        for (int ii=0; ii<32; ii++){
            float4 w = *(const float4*)wp; wp += RD;
            const int i = s*32 + ii;
            #pragma unroll
            for (int j=0;j<4;j++){
                const float xv = hs[j][i];
                acc[j].x = fmaf(xv, w.x, acc[j].x);
                acc[j].y = fmaf(xv, w.y, acc[j].y);
                acc[j].z = fmaf(xv, w.z, acc[j].z);
                acc[j].w = fmaf(xv, w.w, acc[j].w);
            }
        }
        #pragma unroll
        for (int j=0;j<4;j++) *(float4*)&ps[s][j][c0] = acc[j];
    }
    __syncthreads();

    float* rout = (mat==0) ? r_x : (mat==1) ? r_p : r_n;
    #pragma unroll
    for (int rep=0; rep<2; rep++){   // reduce + bias -> rloc + global r
        const int idx = rep*512 + t;
        const int j = idx >> 8, c = idx & 255;
        float v = b2[c];
        #pragma unroll
        for (int ss=0; ss<8; ss++) v += ps[ss][j][c];
        rloc[j][c] = v;
        rout[(row0+j)*RD + c] = v;
    }
    __syncthreads();   // rloc complete; ps free for reuse

    if (mat && t < 256){   // transposed rep copy
        float* rT = (mat==1) ? r_pT : r_nT;
        float4 q = make_float4(rloc[0][t], rloc[1][t], rloc[2][t], rloc[3][t]);
        *(float4*)&rT[t*NN + row0] = q;
    }

    {   // score-net projection: 128 cols, K=256 in 16 slices of 16
        const int cg2 = t & 31, s2 = t >> 5;
        const int cc0 = cg2 << 2;
        const float sgn = (mat==0) ? -1.0f : 1.0f;
        const int base1 = (mat==0) ? 0 : 256;
        const float* p1 = s_w1 + (base1 + s2*16)*SH + cc0;
        const float* p3 = s_w1 + (512   + s2*16)*SH + cc0;
        float4 a[4];
        #pragma unroll
        for (int j=0;j<4;j++) a[j] = make_float4(0.f,0.f,0.f,0.f);
        #pragma unroll 8
        for (int ii=0; ii<16; ii++){
            float4 wa = *(const float4*)p1; p1 += SH;
            float4 wd = *(const float4*)p3; p3 += SH;
            float4 w;
            w.x = fmaf(sgn, wd.x, wa.x);
            w.y = fmaf(sgn, wd.y, wa.y);
            w.z = fmaf(sgn, wd.z, wa.z);
            w.w = fmaf(sgn, wd.w, wa.w);
            const int i = s2*16 + ii;
            #pragma unroll
            for (int j=0;j<4;j++){
                const float xv = rloc[j][i];
                a[j].x = fmaf(xv, w.x, a[j].x);
                a[j].y = fmaf(xv, w.y, a[j].y);
                a[j].z = fmaf(xv, w.z, a[j].z);
                a[j].w = fmaf(xv, w.w, a[j].w);
            }
        }
        float* psf = &ps[0][0][0];   // reuse as [16][4][128]
        #pragma unroll
        for (int j=0;j<4;j++) *(float4*)&psf[(s2*4 + j)*SH + cc0] = a[j];
    }
    __syncthreads();

    {   // reduce 16 slices: 4 rows x 128 cols = 512 outputs
        const float* psf = &ps[0][0][0];
        const int j = t >> 7, c = t & 127;
        float v = 0.f;
        #pragma unroll
        for (int ss=0; ss<16; ss++) v += psf[(ss*4 + j)*SH + c];
        if (mat==0) A_x[(row0+j)*SH + c] = v;
        else        ab4[j][c] = v;
    }
    __syncthreads();
    if (mat && t < 128){
        float* BT = (mat==1) ? BT_p : BT_n;
        float4 q = make_float4(ab4[0][t], ab4[1][t], ab4[2][t], ab4[3][t]);
        *(float4*)&BT[t*NN + row0] = q;
    }
}

// K_SD: unnormalized softmax numerators. 2048 blocks (set x 256 2-row ntiles x
// 4 128-m mtiles) x 256 thr = 8 blocks/CU = 32 waves/CU. Thread = 1 (row, m).
// All LDS reads are wave-uniform broadcasts; norms computed inline.
__global__ __launch_bounds__(256) void k_sd(
    const float* __restrict__ r_x, const float* __restrict__ r_pT, const float* __restrict__ r_nT,
    const float* __restrict__ A_x, const float* __restrict__ BT_p, const float* __restrict__ BT_n,
    const float* __restrict__ s_w1, const float* __restrict__ s_b1,
    const float* __restrict__ s_w2,
    float* __restrict__ E_p, float* __restrict__ E_n, float* __restrict__ Spart)
{
    __shared__ float xs[2][RD];       // 2 KB
    __shared__ float cw2[SH][2];      // 1 KB: A+b1 per row
    __shared__ float2 wz2[SH];        // 1 KB: {w_norm, 0.5*w2}
    __shared__ float nxv[2];
    __shared__ float ssum[2][2];
    const int t = threadIdx.x;
    const int set = blockIdx.x >> 10;
    const int rem = blockIdx.x & 1023;
    const int n0 = (rem >> 2) << 1;
    const int mt = rem & 3;
    const int mbase = mt << 7;
    const int tm = t & 127, tn = t >> 7;
    const int m = mbase + tm;
    const float* yT = set ? r_nT : r_pT;
    const float* BT = set ? BT_n : BT_p;
    float* E = set ? E_n : E_p;

    xs[0][t] = r_x[n0*RD + t];
    xs[1][t] = r_x[(n0+1)*RD + t];
    if (t < SH){
        cw2[t][0] = A_x[n0*SH + t] + s_b1[t];
        cw2[t][1] = A_x[(n0+1)*SH + t] + s_b1[t];
        wz2[t] = make_float2(s_w1[768*SH + t], 0.5f*s_w2[t]);
    }
    __syncthreads();
    {   // x-row norms: waves 0,1 -> rows 0,1
        const int w = t >> 6, lane = t & 63;
        if (w < 2){
            float v = 0.f;
            #pragma unroll
            for (int q=0;q<4;q++){ const float e = xs[w][lane + 64*q]; v = fmaf(e,e,v); }
            #pragma unroll
            for (int off=32; off>=1; off>>=1) v += __shfl_xor(v, off);
            if (lane==0) nxv[w] = v;
        }
    }
    __syncthreads();

    // phase 1: dot(x_row, y_m) + ||y_m||^2 riding the loop
    float d = 0.f, ny = 0.f;
    {
        const float* yp = yT + m;
        #pragma unroll 8
        for (int r=0; r<RD; r++){
            const float y = *yp; yp += NN;
            d  = fmaf(xs[tn][r], y, d);
            ny = fmaf(y, y, ny);
        }
    }
    const float dn = sqrtf(fmaxf(fmaf(-2.f, d, nxv[tn] + ny), 0.f));

    // phase 2: logit via decomposed score net (0.5 of gelu folded into w2)
    float acc = 0.f;
    {
        const float* bp = BT + m;
        #pragma unroll 4
        for (int k=0; k<SH; k++){
            const float b = *bp; bp += NN;
            const float cw = cw2[k][tn];
            const float2 wz = wz2[k];
            const float u = fmaf(dn, wz.x, cw + b);
            const float z  = u * 0.70710678118654752f;
            const float az = fabsf(z);
            const float tt = __builtin_amdgcn_rcpf(fmaf(0.3275911f, az, 1.0f));
            float p = fmaf(1.061405429f, tt, -1.453152027f);
            p = fmaf(p, tt, 1.421413741f);
            p = fmaf(p, tt, -0.284496736f);
            p = fmaf(p, tt, 0.254829592f);
            p = p * tt;
            const float e2 = __builtin_amdgcn_exp2f(z * z * -1.4426950408889634f);
            const float Eq = p * e2;
            const float ope = (u >= 0.0f) ? (2.0f - Eq) : Eq;
            acc = fmaf(wz.y, u * ope, acc);
        }
    }
    // s_b2 omitted (softmax shift-invariant); no max pass (logits are O(1))
    const float ev = __builtin_amdgcn_exp2f(acc * 1.4426950408889634f);
    E[(n0+tn)*NN + m] = ev;

    float v = ev;
    #pragma unroll
    for (int off=32; off>=1; off>>=1) v += __shfl_xor(v, off);
    if ((t & 63) == 0) ssum[tn][(t >> 6) & 1] = v;
    __syncthreads();
    if (t < 2) Spart[(set*4 + mt)*NN + n0 + t] = ssum[t][0] + ssum[t][1];
}

// K_DV: partial einsum over a 64-m slice, both sets combined (pos - neg).
// 1024 blocks (128 4-row ntiles x 8 m-slices). psum[ms][n][c].
__global__ __launch_bounds__(256) void k_dv(
    const float* __restrict__ E_p, const float* __restrict__ E_n,
    const float* __restrict__ Spart,
    const float* __restrict__ r_p, const float* __restrict__ r_n,
    float* __restrict__ psum)
{
    __shared__ float rinv[8];
    __shared__ float wbuf[2][64][4];
    const int t = threadIdx.x;
    const int nt = blockIdx.x >> 3;
    const int ms = blockIdx.x & 7;
    const int n0 = nt << 2, mbase = ms << 6;

    if (t < 8){
        const int se = t >> 2, n = n0 + (t & 3);
        float S = 0.f;
        #pragma unroll
        for (int q=0;q<4;q++) S += Spart[(se*4+q)*NN + n];
        rinv[t] = 1.0f / S;
    }
    __syncthreads();
    #pragma unroll
    for (int rep=0; rep<2; rep++){
        const int idx = rep*256 + t;
        const int se = idx >> 8, j = (idx >> 6) & 3, mm = idx & 63;
        const float* E = se ? E_n : E_p;
        wbuf[se][mm][j] = E[(n0+j)*NN + mbase + mm] * rinv[se*4 + j];
    }
    __syncthreads();

    float acc[4] = {0.f,0.f,0.f,0.f};
    {
        const float* rp = r_p + mbase*RD + t;
        #pragma unroll 4
        for (int mm=0; mm<64; mm++){
            const float rv = *rp; rp += RD;
            const float4 wa = *(const float4*)&wbuf[0][mm][0];
            acc[0]=fmaf(wa.x,rv,acc[0]); acc[1]=fmaf(wa.y,rv,acc[1]);
            acc[2]=fmaf(wa.z,rv,acc[2]); acc[3]=fmaf(wa.w,rv,acc[3]);
        }
    }
    {
        const float* rn = r_n + mbase*RD + t;
        #pragma unroll 4
        for (int mm=0; mm<64; mm++){
            const float rv = -(*rn); rn += RD;
            const float4 wa = *(const float4*)&wbuf[1][mm][0];
            acc[0]=fmaf(wa.x,rv,acc[0]); acc[1]=fmaf(wa.y,rv,acc[1]);
            acc[2]=fmaf(wa.z,rv,acc[2]); acc[3]=fmaf(wa.w,rv,acc[3]);
        }
    }
    float* P = psum + ms*(NN*RD);
    #pragma unroll
    for (int j=0;j<4;j++) P[(n0+j)*RD + t] = acc[j];
}

// K_OUT: dv = sum_ms psum; out = dv @ out_w. 1024 blocks (256 2-row ntiles x
// 4 128-col tiles).
__global__ __launch_bounds__(256) void k_out(
    const float* __restrict__ psum, const float* __restrict__ out_w,
    float* __restrict__ out)
{
    __shared__ float dv2[2][RD];      // 2 KB
    __shared__ float ps[2][2][128];   // 2 KB
    const int t = threadIdx.x;
    const int nt = blockIdx.x >> 2;
    const int cb = (blockIdx.x & 3) << 7;
    const int n0 = nt << 1;

    #pragma unroll
    for (int j=0;j<2;j++){
        float v = 0.f;
        #pragma unroll
        for (int ms=0; ms<8; ms++) v += psum[ms*(NN*RD) + (n0+j)*RD + t];
        dv2[j][t] = v;
    }
    __syncthreads();

    const int cc = t & 127, s = t >> 7;
    float a0 = 0.f, a1 = 0.f;
    const float* wo = out_w + (s*128)*IN + cb + cc;
    #pragma unroll 4
    for (int rr=0; rr<128; rr++){
        const float w = *wo; wo += IN;
        a0 = fmaf(dv2[0][s*128 + rr], w, a0);
        a1 = fmaf(dv2[1][s*128 + rr], w, a1);
    }
    ps[s][0][cc] = a0;
    ps[s][1][cc] = a1;
    __syncthreads();
    {
        const int j = t >> 7, c = t & 127;
        out[(n0+j)*IN + cb + c] = ps[0][j][c] + ps[1][j][c];
    }
}

extern "C" void kernel_launch(void* const* d_in, const int* in_sizes, int n_in,
                              void* d_out, int out_size, void* d_ws, size_t ws_size,
                              hipStream_t stream)
{
    const float* fx  = (const float*)d_in[0];
    const float* fp  = (const float*)d_in[1];
    const float* fn  = (const float*)d_in[2];
    const float* gw1 = (const float*)d_in[3];
    const float* gb1 = (const float*)d_in[4];
    const float* gw2 = (const float*)d_in[5];
    const float* gb2 = (const float*)d_in[6];
    const float* ow  = (const float*)d_in[7];
    const float* sw1 = (const float*)d_in[8];
    const float* sb1 = (const float*)d_in[9];
    const float* sw2 = (const float*)d_in[10];
    float* out = (float*)d_out;

    float* ws   = (float*)d_ws;
    float* r_x  = ws;               // 512*256
    float* r_p  = r_x  + 131072;
    float* r_n  = r_p  + 131072;
    float* r_pT = r_n  + 131072;    // 256*512
    float* r_nT = r_pT + 131072;
    float* A_x  = r_nT + 131072;    // 512*128
    float* BT_p = A_x  + 65536;     // 128*512
    float* BT_n = BT_p + 65536;
    float* E_p  = BT_n + 65536;     // 512*512
    float* E_n  = E_p  + 262144;
    float* Spar = E_n  + 262144;    // 2*4*512
    float* psum = Spar + 4096;      // 8*512*256 = 1M floats (4 MB)

    hipLaunchKernelGGL(k_rep, dim3(384), dim3(512), 0, stream,
                       fx, fp, fn, gw1, gb1, gw2, gb2, sw1,
                       r_x, r_p, r_n, r_pT, r_nT, A_x, BT_p, BT_n);
    hipLaunchKernelGGL(k_sd, dim3(2048), dim3(256), 0, stream,
                       r_x, r_pT, r_nT, A_x, BT_p, BT_n,
                       sw1, sb1, sw2, E_p, E_n, Spar);
    hipLaunchKernelGGL(k_dv, dim3(1024), dim3(256), 0, stream,
                       E_p, E_n, Spar, r_p, r_n, psum);
    hipLaunchKernelGGL(k_out, dim3(1024), dim3(256), 0, stream,
                       psum, ow, out);
}